// Round 1
// baseline (503.579 us; speedup 1.0000x reference)
//
#include <hip/hip_runtime.h>
#include <hip/hip_bf16.h>

// Problem constants (from reference)
#define NH   32
#define HD   128
#define NKV  8
#define GQ   4        // NH / NKV
#define BS   16
#define NB   4096
#define MB   128
#define SEQ  32
#define J    64       // token splits per sequence (one WG each; 8 units = 8 kv heads)
#define UNROLL 4

__constant__ float SCALE_RSQRT = 0.08838834764831845f; // 1/sqrt(128)

typedef float v2f __attribute__((ext_vector_type(2)));

// RNE round f32 -> bf16 -> f32
__device__ __forceinline__ float bf16r(float x) {
  unsigned u = __float_as_uint(x);
  u = (u + 0x7fffu + ((u >> 16) & 1u)) & 0xffff0000u;
  return __uint_as_float(u);
}

// Dequant 4 cache floats: fp8(e4m3fn, RNE) round, * scale, bf16 RNE round.
__device__ __forceinline__ float4 deq4(float4 x, float sc) {
  int p0 = __builtin_amdgcn_cvt_pk_fp8_f32(x.x, x.y, 0, false);
  int p1 = __builtin_amdgcn_cvt_pk_fp8_f32(x.z, x.w, 0, false);
  v2f a = __builtin_amdgcn_cvt_pk_f32_fp8(p0, false);
  v2f b = __builtin_amdgcn_cvt_pk_f32_fp8(p1, false);
  float4 r;
  r.x = bf16r(a.x * sc);
  r.y = bf16r(a.y * sc);
  r.z = bf16r(b.x * sc);
  r.w = bf16r(b.y * sc);
  return r;
}

// ---------------------------------------------------------------------------
// Split-K flash decode, head-folded layout.
// WG = (seq, token-split). The 8 half-wave units of the WG are the 8 KV heads,
// all processing the SAME token set {wgsub, wgsub+64, ...}. A wave64's two
// units (heads 2w, 2w+1) load one contiguous 1 KB span of the 4 KB slot; the
// WG's 4 waves cover the full slot -> 4 KB-contiguous HBM bursts instead of
// random 512 B granules.
// o_part: [SEQ][NKV][J][GQ][HD] f32 ; ml_part: [SEQ][NKV][J][GQ] float2
// ---------------------------------------------------------------------------
__global__ __launch_bounds__(256, 4)
void attn_split(const float* __restrict__ q,
                const float* __restrict__ knew,
                const float* __restrict__ vnew,
                const float* __restrict__ k_cache,
                const float* __restrict__ v_cache,
                const float* __restrict__ k_scale,
                const float* __restrict__ v_scale,
                const int* __restrict__ block_tables,
                const int* __restrict__ context_lens,
                float* __restrict__ o_part,
                float2* __restrict__ ml_part) {
  const int wg = blockIdx.x;
  const int wgsub = wg % J;             // token split id: tokens t == wgsub (mod J)
  const int s = wg / J;
  const int tid = threadIdx.x;
  const int lane = tid & 31;
  const int h = tid >> 5;               // unit == kv head (0..7)
  const int dbase = lane * 4;

  __shared__ int bt[MB];                // this seq's block table

  // q fragment, pre-scaled (independent of bt -> issue before the barrier)
  float4 qv[GQ];
#pragma unroll
  for (int g = 0; g < GQ; ++g) {
    float4 t = *(const float4*)(q + ((size_t)s * NH + h * GQ + g) * HD + dbase);
    qv[g].x = t.x * SCALE_RSQRT;
    qv[g].y = t.y * SCALE_RSQRT;
    qv[g].z = t.z * SCALE_RSQRT;
    qv[g].w = t.w * SCALE_RSQRT;
  }

  if (tid < MB) bt[tid] = block_tables[s * MB + tid];
  __syncthreads();

  const int ctx = context_lens[s];
  const int last = ctx - 1;             // position of the fresh token
  const float ks = k_scale[h];
  const float vs = v_scale[h];

  float m[GQ], l[GQ];
  float4 oacc[GQ];
#pragma unroll
  for (int g = 0; g < GQ; ++g) {
    m[g] = -1e30f;
    l[g] = 0.0f;
    oacc[g] = make_float4(0.f, 0.f, 0.f, 0.f);
  }

  // ---- fresh token (position last): quantize from knew/vnew, bypass cache
  if (wgsub == (last & (J - 1))) {
    float4 kk = *(const float4*)(knew + ((size_t)s * NKV + h) * HD + dbase);
    float4 vt = *(const float4*)(vnew + ((size_t)s * NKV + h) * HD + dbase);
    kk.x /= ks; kk.y /= ks; kk.z /= ks; kk.w /= ks;
    vt.x /= vs; vt.y /= vs; vt.z /= vs; vt.w /= vs;
    kk = deq4(kk, ks);
    vt = deq4(vt, vs);
#pragma unroll
    for (int g = 0; g < GQ; ++g) {
      float d = kk.x * qv[g].x + kk.y * qv[g].y + kk.z * qv[g].z + kk.w * qv[g].w;
      d += __shfl_xor(d, 1);
      d += __shfl_xor(d, 2);
      d += __shfl_xor(d, 4);
      d += __shfl_xor(d, 8);
      d += __shfl_xor(d, 16);
      m[g] = d;
      l[g] = 1.0f;                      // exp(d - d)
      oacc[g] = vt;                     // p * v with p = 1
    }
  }

  // ---- main loop over this split's strided tokens (skip `last`)
  for (int t0 = wgsub; t0 < ctx; t0 += J * UNROLL) {
    float4 kk[UNROLL], vv[UNROLL];
    bool val[UNROLL];
#pragma unroll
    for (int i = 0; i < UNROLL; ++i) {
      int t = t0 + i * J;
      val[i] = (t < ctx) && (t != last);
      kk[i] = make_float4(0.f, 0.f, 0.f, 0.f);
      vv[i] = make_float4(0.f, 0.f, 0.f, 0.f);
      if (val[i]) {
        int blk = bt[t >> 4];
        size_t off = (((size_t)blk * BS + (t & (BS - 1))) * NKV + h) * HD + dbase;
        kk[i] = *(const float4*)(k_cache + off);
        vv[i] = *(const float4*)(v_cache + off);
      }
    }

    float sc[UNROLL][GQ];
#pragma unroll
    for (int i = 0; i < UNROLL; ++i) {
      float4 kd = deq4(kk[i], ks);
      vv[i] = deq4(vv[i], vs);
#pragma unroll
      for (int g = 0; g < GQ; ++g) {
        float d = kd.x * qv[g].x + kd.y * qv[g].y + kd.z * qv[g].z + kd.w * qv[g].w;
        d += __shfl_xor(d, 1);
        d += __shfl_xor(d, 2);
        d += __shfl_xor(d, 4);
        d += __shfl_xor(d, 8);
        d += __shfl_xor(d, 16);
        sc[i][g] = val[i] ? d : -1e30f;
      }
    }

#pragma unroll
    for (int g = 0; g < GQ; ++g) {
      float tm = sc[0][g];
#pragma unroll
      for (int i = 1; i < UNROLL; ++i) tm = fmaxf(tm, sc[i][g]);
      float mnew = fmaxf(m[g], tm);
      float alpha = __expf(m[g] - mnew);
      float p[UNROLL];
      float lad = 0.f;
#pragma unroll
      for (int i = 0; i < UNROLL; ++i) {
        p[i] = __expf(sc[i][g] - mnew);
        lad += p[i];
      }
      l[g] = l[g] * alpha + lad;
      float4 acc = make_float4(0.f, 0.f, 0.f, 0.f);
#pragma unroll
      for (int i = 0; i < UNROLL; ++i) {
        acc.x += p[i] * vv[i].x;
        acc.y += p[i] * vv[i].y;
        acc.z += p[i] * vv[i].z;
        acc.w += p[i] * vv[i].w;
      }
      oacc[g].x = oacc[g].x * alpha + acc.x;
      oacc[g].y = oacc[g].y * alpha + acc.y;
      oacc[g].z = oacc[g].z * alpha + acc.z;
      oacc[g].w = oacc[g].w * alpha + acc.w;
      m[g] = mnew;
    }
  }

  // ---- write this unit's partial directly (no intra-WG combine needed:
  //      every unit is a different head)
  const size_t pb = (((size_t)s * NKV + h) * J + wgsub) * GQ;
#pragma unroll
  for (int g = 0; g < GQ; ++g)
    *(float4*)(o_part + (pb + g) * HD + dbase) = oacc[g];
  if (lane == 0) {
#pragma unroll
    for (int g = 0; g < GQ; ++g)
      ml_part[pb + g] = make_float2(m[g], l[g]);
  }
}

// ---------------------------------------------------------------------------
// Combine the J split partials per (s,h,g)
// ---------------------------------------------------------------------------
__global__ void combine_splits(const float* __restrict__ o_part,
                               const float2* __restrict__ ml_part,
                               float* __restrict__ out) {
  const int b = blockIdx.x;          // (s*NKV + h)*GQ + g
  const int g = b % GQ;
  const int sh = b / GQ;             // s*NKV + h
  const int h = sh % NKV;
  const int s = sh / NKV;
  const int d = threadIdx.x;         // 0..127
  const size_t mlbase = (size_t)sh * J * GQ + g;

  float M = -1e30f;
  for (int i = 0; i < J; ++i)
    M = fmaxf(M, ml_part[mlbase + (size_t)i * GQ].x);

  float L = 0.f, acc = 0.f;
  for (int i = 0; i < J; ++i) {
    float2 t = ml_part[mlbase + (size_t)i * GQ];
    float w = __expf(t.x - M);
    L += t.y * w;
    acc += w * o_part[(mlbase + (size_t)i * GQ) * HD + d];
  }
  out[((size_t)s * NH + h * GQ + g) * HD + d] = acc / L;
}

// ---------------------------------------------------------------------------
extern "C" void kernel_launch(void* const* d_in, const int* in_sizes, int n_in,
                              void* d_out, int out_size, void* d_ws, size_t ws_size,
                              hipStream_t stream) {
  const float* q        = (const float*)d_in[0];
  const float* k        = (const float*)d_in[1];
  const float* v        = (const float*)d_in[2];
  const float* k_cache  = (const float*)d_in[3];
  const float* v_cache  = (const float*)d_in[4];
  const float* k_scale  = (const float*)d_in[5];
  const float* v_scale  = (const float*)d_in[6];
  const int*   btables  = (const int*)d_in[8];
  const int*   ctx_lens = (const int*)d_in[9];
  float*       out      = (float*)d_out;

  // workspace: o_part (33.55 MB) then ml_part (512 KB)
  float*  o_part  = (float*)d_ws;
  float2* ml_part = (float2*)((char*)d_ws +
                     (size_t)SEQ * NKV * J * GQ * HD * sizeof(float));

  attn_split<<<SEQ * J, 256, 0, stream>>>(
      q, k, v, k_cache, v_cache, k_scale, v_scale, btables, ctx_lens,
      o_part, ml_part);

  combine_splits<<<SEQ * NKV * GQ, 128, 0, stream>>>(o_part, ml_part, out);
}

// Round 2
// 501.176 us; speedup vs baseline: 1.0048x; 1.0048x over previous
//
#include <hip/hip_runtime.h>
#include <hip/hip_bf16.h>

// Problem constants (from reference)
#define NH   32
#define HD   128
#define NKV  8
#define GQ   4        // NH / NKV
#define BS   16
#define NB   4096
#define MB   128
#define SEQ  32
#define UNITS 16      // 32-lane token-split units per WG (512 threads)
#define UNROLL 4

__constant__ float SCALE_RSQRT = 0.08838834764831845f; // 1/sqrt(128)

typedef float v2f __attribute__((ext_vector_type(2)));

// RNE round f32 -> bf16 -> f32
__device__ __forceinline__ float bf16r(float x) {
  unsigned u = __float_as_uint(x);
  u = (u + 0x7fffu + ((u >> 16) & 1u)) & 0xffff0000u;
  return __uint_as_float(u);
}

// Dequant 4 cache floats: fp8(e4m3fn, RNE) round, * scale, bf16 RNE round.
// Cache values are already fp8-representable, so the fp8 pass is exact for
// them; for the fresh token we pre-divide by scale and this performs the
// actual quantization, matching the reference bit-for-bit.
__device__ __forceinline__ float4 deq4(float4 x, float sc) {
  int p0 = __builtin_amdgcn_cvt_pk_fp8_f32(x.x, x.y, 0, false);
  int p1 = __builtin_amdgcn_cvt_pk_fp8_f32(x.z, x.w, 0, false);
  v2f a = __builtin_amdgcn_cvt_pk_f32_fp8(p0, false);
  v2f b = __builtin_amdgcn_cvt_pk_f32_fp8(p1, false);
  float4 r;
  r.x = bf16r(a.x * sc);
  r.y = bf16r(a.y * sc);
  r.z = bf16r(b.x * sc);
  r.w = bf16r(b.y * sc);
  return r;
}

// ---------------------------------------------------------------------------
// Fully fused single-pass GQA flash decode. One WG per (s, kv-head):
// grid = 256 (1 WG/CU), 512 threads = 16 half-wave units. Unit u owns tokens
// {u, u+16, u+32, ...}; softmax state is lane-local (no barriers in the main
// loop). Epilogue combines the 16 units through LDS and writes `out`
// directly -- no workspace partials, no second kernel.
// ---------------------------------------------------------------------------
__global__ __launch_bounds__(512, 2)
void attn_fused(const float* __restrict__ q,
                const float* __restrict__ knew,
                const float* __restrict__ vnew,
                const float* __restrict__ k_cache,
                const float* __restrict__ v_cache,
                const float* __restrict__ k_scale,
                const float* __restrict__ v_scale,
                const int* __restrict__ block_tables,
                const int* __restrict__ context_lens,
                float* __restrict__ out) {
  const int wg = blockIdx.x;
  const int h = wg % NKV;
  const int s = wg / NKV;
  const int tid = threadIdx.x;
  const int lane = tid & 31;
  const int unit = tid >> 5;            // 0..15
  const int dbase = lane * 4;

  __shared__ int bt[MB];                // this seq's block table (512 B)
  __shared__ float so[UNITS][GQ][HD];   // 32 KB epilogue buffer
  __shared__ float2 sml[UNITS][GQ];

  // q fragment, pre-scaled (independent of bt -> issue before the barrier)
  float4 qv[GQ];
#pragma unroll
  for (int g = 0; g < GQ; ++g) {
    float4 t = *(const float4*)(q + ((size_t)s * NH + h * GQ + g) * HD + dbase);
    qv[g].x = t.x * SCALE_RSQRT;
    qv[g].y = t.y * SCALE_RSQRT;
    qv[g].z = t.z * SCALE_RSQRT;
    qv[g].w = t.w * SCALE_RSQRT;
  }

  if (tid < MB) bt[tid] = block_tables[s * MB + tid];
  __syncthreads();

  const int ctx = context_lens[s];
  const int last = ctx - 1;             // position of the fresh token
  const float ks = k_scale[h];
  const float vs = v_scale[h];

  float m[GQ], l[GQ];
  float4 oacc[GQ];
#pragma unroll
  for (int g = 0; g < GQ; ++g) {
    m[g] = -1e30f;
    l[g] = 0.0f;
    oacc[g] = make_float4(0.f, 0.f, 0.f, 0.f);
  }

  // ---- fresh token (position last): quantize from knew/vnew, bypass cache
  if (unit == (last & (UNITS - 1))) {
    float4 kk = *(const float4*)(knew + ((size_t)s * NKV + h) * HD + dbase);
    float4 vt = *(const float4*)(vnew + ((size_t)s * NKV + h) * HD + dbase);
    kk.x /= ks; kk.y /= ks; kk.z /= ks; kk.w /= ks;
    vt.x /= vs; vt.y /= vs; vt.z /= vs; vt.w /= vs;
    kk = deq4(kk, ks);
    vt = deq4(vt, vs);
#pragma unroll
    for (int g = 0; g < GQ; ++g) {
      float d = kk.x * qv[g].x + kk.y * qv[g].y + kk.z * qv[g].z + kk.w * qv[g].w;
      d += __shfl_xor(d, 1);
      d += __shfl_xor(d, 2);
      d += __shfl_xor(d, 4);
      d += __shfl_xor(d, 8);
      d += __shfl_xor(d, 16);
      m[g] = d;
      l[g] = 1.0f;                      // exp(d - d)
      oacc[g] = vt;                     // p * v with p = 1
    }
  }

  // ---- main loop over this unit's strided tokens (skip `last`)
  for (int t0 = unit; t0 < ctx; t0 += UNITS * UNROLL) {
    float4 kk[UNROLL], vv[UNROLL];
    bool val[UNROLL];
#pragma unroll
    for (int i = 0; i < UNROLL; ++i) {
      int t = t0 + i * UNITS;
      val[i] = (t < ctx) && (t != last);
      kk[i] = make_float4(0.f, 0.f, 0.f, 0.f);
      vv[i] = make_float4(0.f, 0.f, 0.f, 0.f);
      if (val[i]) {
        int blk = bt[t >> 4];
        size_t off = (((size_t)blk * BS + (t & (BS - 1))) * NKV + h) * HD + dbase;
        kk[i] = *(const float4*)(k_cache + off);
        vv[i] = *(const float4*)(v_cache + off);
      }
    }

    float sc[UNROLL][GQ];
#pragma unroll
    for (int i = 0; i < UNROLL; ++i) {
      float4 kd = deq4(kk[i], ks);
      vv[i] = deq4(vv[i], vs);
#pragma unroll
      for (int g = 0; g < GQ; ++g) {
        float d = kd.x * qv[g].x + kd.y * qv[g].y + kd.z * qv[g].z + kd.w * qv[g].w;
        d += __shfl_xor(d, 1);
        d += __shfl_xor(d, 2);
        d += __shfl_xor(d, 4);
        d += __shfl_xor(d, 8);
        d += __shfl_xor(d, 16);
        sc[i][g] = val[i] ? d : -1e30f;
      }
    }

#pragma unroll
    for (int g = 0; g < GQ; ++g) {
      float tm = sc[0][g];
#pragma unroll
      for (int i = 1; i < UNROLL; ++i) tm = fmaxf(tm, sc[i][g]);
      float mnew = fmaxf(m[g], tm);
      float alpha = __expf(m[g] - mnew);
      float p[UNROLL];
      float lad = 0.f;
#pragma unroll
      for (int i = 0; i < UNROLL; ++i) {
        p[i] = __expf(sc[i][g] - mnew);
        lad += p[i];
      }
      l[g] = l[g] * alpha + lad;
      float4 acc = make_float4(0.f, 0.f, 0.f, 0.f);
#pragma unroll
      for (int i = 0; i < UNROLL; ++i) {
        acc.x += p[i] * vv[i].x;
        acc.y += p[i] * vv[i].y;
        acc.z += p[i] * vv[i].z;
        acc.w += p[i] * vv[i].w;
      }
      oacc[g].x = oacc[g].x * alpha + acc.x;
      oacc[g].y = oacc[g].y * alpha + acc.y;
      oacc[g].z = oacc[g].z * alpha + acc.z;
      oacc[g].w = oacc[g].w * alpha + acc.w;
      m[g] = mnew;
    }
  }

  // ---- intra-WG combine of the 16 units, write out directly
#pragma unroll
  for (int g = 0; g < GQ; ++g)
    *(float4*)&so[unit][g][dbase] = oacc[g];
  if (lane == 0) {
#pragma unroll
    for (int g = 0; g < GQ; ++g) sml[unit][g] = make_float2(m[g], l[g]);
  }
  __syncthreads();

  if (tid < 128) {
    int g = tid >> 5;
    int ln = tid & 31;
    float M = -1e30f;
#pragma unroll
    for (int u = 0; u < UNITS; ++u) M = fmaxf(M, sml[u][g].x);
    float L = 0.f;
    float4 acc = make_float4(0.f, 0.f, 0.f, 0.f);
#pragma unroll
    for (int u = 0; u < UNITS; ++u) {
      float w = __expf(sml[u][g].x - M);
      L += sml[u][g].y * w;
      float4 t = *(const float4*)&so[u][g][ln * 4];
      acc.x += w * t.x;
      acc.y += w * t.y;
      acc.z += w * t.z;
      acc.w += w * t.w;
    }
    float rL = 1.0f / L;
    acc.x *= rL; acc.y *= rL; acc.z *= rL; acc.w *= rL;
    *(float4*)(out + ((size_t)s * NH + h * GQ + g) * HD + ln * 4) = acc;
  }
}

// ---------------------------------------------------------------------------
extern "C" void kernel_launch(void* const* d_in, const int* in_sizes, int n_in,
                              void* d_out, int out_size, void* d_ws, size_t ws_size,
                              hipStream_t stream) {
  const float* q        = (const float*)d_in[0];
  const float* k        = (const float*)d_in[1];
  const float* v        = (const float*)d_in[2];
  const float* k_cache  = (const float*)d_in[3];
  const float* v_cache  = (const float*)d_in[4];
  const float* k_scale  = (const float*)d_in[5];
  const float* v_scale  = (const float*)d_in[6];
  const int*   btables  = (const int*)d_in[8];
  const int*   ctx_lens = (const int*)d_in[9];
  float*       out      = (float*)d_out;

  (void)d_ws; (void)ws_size;

  attn_fused<<<SEQ * NKV, 512, 0, stream>>>(
      q, k, v, k_cache, v_cache, k_scale, v_scale, btables, ctx_lens, out);
}